// Round 7
// baseline (231.863 us; speedup 1.0000x reference)
//
#include <hip/hip_runtime.h>

#define B_  2
#define NX_ 512
#define NC_ 4096
#define D_  1024
#define H_  16
#define HD_ 64
#define NT_ (NX_ + NC_)   // 4608
#define NSPLIT 4
#define KBS (NT_ / 64 / NSPLIT)   // 18 key-blocks per split

typedef float  floatx4  __attribute__((ext_vector_type(4)));
typedef __bf16 bf16x8   __attribute__((ext_vector_type(8)));
typedef unsigned short ushort8v __attribute__((ext_vector_type(8)));

__device__ __forceinline__ bf16x8 as_bf16x8(ushort8v u) {
    union { ushort8v u; bf16x8 b; } c; c.u = u; return c.b;
}
// fp32 -> bf16 round-to-nearest-even
__device__ __forceinline__ unsigned short f2bf(float f) {
    unsigned u = __float_as_uint(f);
    u += 0x7FFF + ((u >> 16) & 1);
    return (unsigned short)(u >> 16);
}

// ---------------- LayerNorm: x fp32 -> xn bf16 ----------------
__global__ __launch_bounds__(256)
void ln_kernel(const float* __restrict__ x,
               const float* __restrict__ lw,
               const float* __restrict__ lb,
               unsigned short* __restrict__ xnb) {
    int row = blockIdx.x;
    int tid = threadIdx.x;
    float4 v = reinterpret_cast<const float4*>(x)[(size_t)row * (D_ / 4) + tid];
    float s  = v.x + v.y + v.z + v.w;
    float s2 = v.x * v.x + v.y * v.y + v.z * v.z + v.w * v.w;
    #pragma unroll
    for (int off = 32; off > 0; off >>= 1) {
        s  += __shfl_down(s, off);
        s2 += __shfl_down(s2, off);
    }
    __shared__ float sm[4], sm2[4], stat[2];
    int wv = tid >> 6;
    if ((tid & 63) == 0) { sm[wv] = s; sm2[wv] = s2; }
    __syncthreads();
    if (tid == 0) {
        float S  = sm[0] + sm[1] + sm[2] + sm[3];
        float S2 = sm2[0] + sm2[1] + sm2[2] + sm2[3];
        float mu  = S * (1.0f / D_);
        float var = fmaxf(S2 * (1.0f / D_) - mu * mu, 0.0f);
        stat[0] = mu;
        stat[1] = rsqrtf(var + 1e-5f);
    }
    __syncthreads();
    float mu = stat[0], rs = stat[1];
    float4 w4 = reinterpret_cast<const float4*>(lw)[tid];
    float4 b4 = reinterpret_cast<const float4*>(lb)[tid];
    ushort4 o;
    o.x = f2bf((v.x - mu) * rs * w4.x + b4.x);
    o.y = f2bf((v.y - mu) * rs * w4.y + b4.y);
    o.z = f2bf((v.z - mu) * rs * w4.z + b4.z);
    o.w = f2bf((v.w - mu) * rs * w4.w + b4.w);
    reinterpret_cast<ushort4*>(xnb)[(size_t)row * (D_ / 4) + tid] = o;
}

// ---------------- transpose+cast: W (KxN fp32) -> WT (NxK bf16), 64x64 tiles ----------------
__global__ __launch_bounds__(256)
void tcast_kernel(const float* __restrict__ W, unsigned short* __restrict__ WT) {
    __shared__ unsigned short T[64][72];
    int row0 = blockIdx.y * 64, col0 = blockIdx.x * 64;
    int tid = threadIdx.x;
    int r = tid >> 2, ch = (tid & 3) * 16;
    const float* src = W + (size_t)(row0 + r) * D_ + col0 + ch;
    unsigned short vals[16];
    #pragma unroll
    for (int t = 0; t < 4; ++t) {
        float4 v = reinterpret_cast<const float4*>(src)[t];
        vals[t*4+0] = f2bf(v.x); vals[t*4+1] = f2bf(v.y);
        vals[t*4+2] = f2bf(v.z); vals[t*4+3] = f2bf(v.w);
    }
    #pragma unroll
    for (int i = 0; i < 16; ++i) T[ch + i][r] = vals[i];
    __syncthreads();
    unsigned short* dst = WT + (size_t)(col0 + r) * D_ + row0 + ch;
    uint4 o0 = *reinterpret_cast<uint4*>(&T[r][ch]);
    uint4 o1 = *reinterpret_cast<uint4*>(&T[r][ch + 8]);
    *reinterpret_cast<uint4*>(dst)     = o0;
    *reinterpret_cast<uint4*>(dst + 8) = o1;
}

// ---------------- cast c fp32 -> bf16 ----------------
__global__ __launch_bounds__(256)
void cast_kernel(const float* __restrict__ in, unsigned short* __restrict__ outp) {
    size_t i = ((size_t)blockIdx.x * 256 + threadIdx.x) * 4;
    float4 v = *reinterpret_cast<const float4*>(in + i);
    ushort4 o;
    o.x = f2bf(v.x); o.y = f2bf(v.y); o.z = f2bf(v.z); o.w = f2bf(v.w);
    *reinterpret_cast<ushort4*>(outp + i) = o;
}

// ---------------- mask (int 0/1) -> bitmask ----------------
__global__ __launch_bounds__(256)
void pack_mask_kernel(const int* __restrict__ mask, unsigned* __restrict__ bits) {
    size_t w = (size_t)blockIdx.x * 256 + threadIdx.x;
    const int* src = mask + w * 32;
    unsigned b = 0;
    #pragma unroll
    for (int c = 0; c < 8; ++c) {
        int4 v = reinterpret_cast<const int4*>(src)[c];
        b |= (v.x != 0 ? 1u : 0u) << (c * 4 + 0);
        b |= (v.y != 0 ? 1u : 0u) << (c * 4 + 1);
        b |= (v.z != 0 ? 1u : 0u) << (c * 4 + 2);
        b |= (v.w != 0 ? 1u : 0u) << (c * 4 + 3);
    }
    bits[w] = b;
}

// ---------------- kv0: out2[b,h,n,d] = c[b,n,h*64+d] (fp32) — runs LAST ----------------
__global__ __launch_bounds__(256)
void kv0_kernel(const float* __restrict__ c, float* __restrict__ out2) {
    size_t i = (size_t)blockIdx.x * 256 + threadIdx.x;
    int d4 = (int)(i & 15);
    size_t r = i >> 4;
    int n = (int)(r % NC_);
    size_t r2 = r / NC_;
    int h = (int)(r2 & (H_ - 1));
    int b = (int)(r2 >> 4);
    float4 v = *reinterpret_cast<const float4*>(c + ((size_t)(b * NC_ + n)) * D_ + h * HD_ + d4 * 4);
    reinterpret_cast<float4*>(out2)[i] = v;
}

// ---------------- MFMA GEMM: C = A(bf16 1024xK) @ B, B given as BT(bf16 NxK) ----------------
__global__ __launch_bounds__(256)
void gemm_bt_kernel(const unsigned short* __restrict__ A, const unsigned short* __restrict__ BT,
                    float* __restrict__ Cf, unsigned short* __restrict__ Cb) {
    __shared__ unsigned short As[64][72];
    __shared__ unsigned short Bs[64][72];
    int tid = threadIdx.x;
    int lane = tid & 63, wave = tid >> 6;
    int m16 = lane & 15, g = lane >> 4, g8 = g * 8;
    int row0 = blockIdx.y * 64, col0 = blockIdx.x * 64;
    int r = tid >> 2, ch = (tid & 3) * 16;

    floatx4 acc[4];
    #pragma unroll
    for (int t = 0; t < 4; ++t) acc[t] = (floatx4){0.f, 0.f, 0.f, 0.f};

    for (int kc = 0; kc < 16; ++kc) {
        int k0 = kc * 64;
        const unsigned short* asrc = A  + (size_t)(row0 + r) * D_ + k0 + ch;
        const unsigned short* bsrc = BT + (size_t)(col0 + r) * D_ + k0 + ch;
        uint4 a0 = *reinterpret_cast<const uint4*>(asrc);
        uint4 a1 = *reinterpret_cast<const uint4*>(asrc + 8);
        uint4 b0 = *reinterpret_cast<const uint4*>(bsrc);
        uint4 b1 = *reinterpret_cast<const uint4*>(bsrc + 8);
        *reinterpret_cast<uint4*>(&As[r][ch])     = a0;
        *reinterpret_cast<uint4*>(&As[r][ch + 8]) = a1;
        *reinterpret_cast<uint4*>(&Bs[r][ch])     = b0;
        *reinterpret_cast<uint4*>(&Bs[r][ch + 8]) = b1;
        __syncthreads();
        bf16x8 fa0 = as_bf16x8(*reinterpret_cast<ushort8v*>(&As[16 * wave + m16][g8]));
        bf16x8 fa1 = as_bf16x8(*reinterpret_cast<ushort8v*>(&As[16 * wave + m16][32 + g8]));
        #pragma unroll
        for (int t = 0; t < 4; ++t) {
            bf16x8 fb0 = as_bf16x8(*reinterpret_cast<ushort8v*>(&Bs[16 * t + m16][g8]));
            bf16x8 fb1 = as_bf16x8(*reinterpret_cast<ushort8v*>(&Bs[16 * t + m16][32 + g8]));
            acc[t] = __builtin_amdgcn_mfma_f32_16x16x32_bf16(fa0, fb0, acc[t], 0, 0, 0);
            acc[t] = __builtin_amdgcn_mfma_f32_16x16x32_bf16(fa1, fb1, acc[t], 0, 0, 0);
        }
        __syncthreads();
    }
    #pragma unroll
    for (int t = 0; t < 4; ++t) {
        #pragma unroll
        for (int reg = 0; reg < 4; ++reg) {
            size_t idx = (size_t)(row0 + 16 * wave + g * 4 + reg) * D_ + col0 + 16 * t + m16;
            if (Cb) Cb[idx] = f2bf(acc[t][reg]);
            else    Cf[idx] = acc[t][reg];
        }
    }
}

// ---------------- MFMA flash attention, split-K x4, atomic accumulation ----------------
// grid 1024 = (split:4, b:2, h:16, qt:8); 256 thr / 4 waves; wave owns 16 q-rows.
// Linear fixed-ref softmax p=exp(s/8-64): split partials atomically add into gacc.
// Kts: [64][72] pad + chunk rotation pc=((key>>3)+(d>>3))&7:
//   writes 16 banks x 2-way (free), PV b128 reads conflict-free (pad spreads rows).
__global__ __launch_bounds__(256, 4)
void attn_kernel(const unsigned short* __restrict__ qbf,
                 const unsigned short* __restrict__ cbf,
                 const unsigned* __restrict__ maskbits,
                 float* __restrict__ gacc, float* __restrict__ gacc_l) {
    int blk   = blockIdx.x;
    int split = blk >> 8;
    int rblk  = blk & 255;
    int qt = rblk & 7;
    int h  = (rblk >> 3) & 15;
    int b  = rblk >> 7;
    int tid  = threadIdx.x;
    int lane = tid & 63;
    int wave = tid >> 6;
    int m16  = lane & 15;
    int g    = lane >> 4;
    int g8   = g * 8;

    __shared__ unsigned short Ks [64][72];
    __shared__ unsigned short Kts[64][72];
    __shared__ unsigned short Ps [64][72];

    // Q A-frags direct from global (once)
    const unsigned short* qrow = qbf + ((size_t)(b * NX_ + qt * 64 + 16 * wave + m16)) * D_ + h * HD_;
    bf16x8 qa0 = as_bf16x8(*reinterpret_cast<const ushort8v*>(qrow + g8));
    bf16x8 qa1 = as_bf16x8(*reinterpret_cast<const ushort8v*>(qrow + 32 + g8));

    floatx4 acc_o[4];
    #pragma unroll
    for (int td = 0; td < 4; ++td) acc_o[td] = (floatx4){0.f, 0.f, 0.f, 0.f};
    float l_acc[4] = {0.f, 0.f, 0.f, 0.f};

    int keyl = tid >> 2, dch = (tid & 3) * 16;

    for (int i = 0; i < KBS; ++i) {
        int kb = split * KBS + i;
        __syncthreads();                       // prior PV done with Ks/Kts
        // ---- stage K tile (bf16): Ks rows + rotated Kts ----
        const unsigned short* src = (kb < 8)
            ? qbf + ((size_t)(b * NX_ + kb * 64 + keyl)) * D_ + h * HD_ + dch
            : cbf + ((size_t)(b * NC_ + kb * 64 - NX_ + keyl)) * D_ + h * HD_ + dch;
        union { uint4 v[2]; unsigned short s[16]; } u;
        u.v[0] = *reinterpret_cast<const uint4*>(src);
        u.v[1] = *reinterpret_cast<const uint4*>(src + 8);
        *reinterpret_cast<uint4*>(&Ks[keyl][dch])     = u.v[0];
        *reinterpret_cast<uint4*>(&Ks[keyl][dch + 8]) = u.v[1];
        #pragma unroll
        for (int k = 0; k < 16; ++k) {
            int d = dch + k;
            int pc = ((keyl >> 3) + (d >> 3)) & 7;
            Kts[d][pc * 8 + (keyl & 7)] = u.s[k];
        }
        __syncthreads();

        // ---- S = Q @ K^T ----
        floatx4 accs[4];
        #pragma unroll
        for (int t = 0; t < 4; ++t) {
            bf16x8 b0 = as_bf16x8(*reinterpret_cast<ushort8v*>(&Ks[16 * t + m16][g8]));
            bf16x8 b1 = as_bf16x8(*reinterpret_cast<ushort8v*>(&Ks[16 * t + m16][32 + g8]));
            floatx4 d = (floatx4){0.f, 0.f, 0.f, 0.f};
            d = __builtin_amdgcn_mfma_f32_16x16x32_bf16(qa0, b0, d, 0, 0, 0);
            d = __builtin_amdgcn_mfma_f32_16x16x32_bf16(qa1, b1, d, 0, 0, 0);
            accs[t] = d;
        }

        unsigned mw0[4], mw1[4];
        if (kb >= 8) {
            #pragma unroll
            for (int r = 0; r < 4; ++r) {
                size_t mi = ((size_t)(b * NX_ + qt * 64 + 16 * wave + g * 4 + r)) * (NC_ / 32)
                          + (size_t)(kb - 8) * 2;
                uint2 w = *reinterpret_cast<const uint2*>(&maskbits[mi]);
                mw0[r] = w.x; mw1[r] = w.y;
            }
        }

        // ---- p = exp(s/8 - 64), masked -> 0; P strip; row partial sums ----
        float psum[4] = {0.f, 0.f, 0.f, 0.f};
        #pragma unroll
        for (int t = 0; t < 4; ++t) {
            #pragma unroll
            for (int r = 0; r < 4; ++r) {
                float s = accs[t][r] * 0.125f;
                float p = __expf(fminf(s, 64.0f) - 64.0f);
                if (kb >= 8) {
                    unsigned w = (t < 2) ? mw0[r] : mw1[r];
                    unsigned bit = (w >> ((16 * t + m16) & 31)) & 1u;
                    p = bit ? p : 0.0f;
                }
                psum[r] += p;
                Ps[16 * wave + g * 4 + r][16 * t + m16] = f2bf(p);
            }
        }
        #pragma unroll
        for (int r = 0; r < 4; ++r) {
            float v = psum[r];
            v += __shfl_xor(v, 1, 16);
            v += __shfl_xor(v, 2, 16);
            v += __shfl_xor(v, 4, 16);
            v += __shfl_xor(v, 8, 16);
            l_acc[r] += v;
        }
        asm volatile("s_waitcnt lgkmcnt(0)" ::: "memory");   // own-strip Ps round-trip

        // ---- O += P @ V (V rows from rotated Kts) ----
        bf16x8 p0 = as_bf16x8(*reinterpret_cast<ushort8v*>(&Ps[16 * wave + m16][g8]));
        bf16x8 p1 = as_bf16x8(*reinterpret_cast<ushort8v*>(&Ps[16 * wave + m16][32 + g8]));
        #pragma unroll
        for (int td = 0; td < 4; ++td) {
            int row = 16 * td + m16;
            int rh = row >> 3;
            bf16x8 v0 = as_bf16x8(*reinterpret_cast<ushort8v*>(&Kts[row][((g + rh) & 7) * 8]));
            bf16x8 v1 = as_bf16x8(*reinterpret_cast<ushort8v*>(&Kts[row][((4 + g + rh) & 7) * 8]));
            acc_o[td] = __builtin_amdgcn_mfma_f32_16x16x32_bf16(p0, v0, acc_o[td], 0, 0, 0);
            acc_o[td] = __builtin_amdgcn_mfma_f32_16x16x32_bf16(p1, v1, acc_o[td], 0, 0, 0);
        }
    }

    // ---- epilogue: atomically accumulate partial O and l ----
    #pragma unroll
    for (int r = 0; r < 4; ++r) {
        int qrow_ = qt * 64 + 16 * wave + g * 4 + r;
        float* dst = gacc + ((size_t)(b * NX_ + qrow_)) * D_ + h * HD_;
        #pragma unroll
        for (int td = 0; td < 4; ++td)
            unsafeAtomicAdd(&dst[16 * td + m16], acc_o[td][r]);
        if (m16 == 0)
            unsafeAtomicAdd(&gacc_l[(size_t)(b * NX_ + qrow_) * H_ + h], l_acc[r]);
    }
}

// ---------------- combine: normalize accumulated O, write bf16 ----------------
__global__ __launch_bounds__(256)
void combine_kernel(const float* __restrict__ gacc, const float* __restrict__ gacc_l,
                    unsigned short* __restrict__ abuf) {
    size_t gtid = (size_t)blockIdx.x * 256 + threadIdx.x;
    size_t idx4 = gtid * 4;
    size_t bq = idx4 >> 10;
    int h = (int)((idx4 & 1023) >> 6);
    float4 v = *reinterpret_cast<const float4*>(gacc + idx4);
    float inv = 1.0f / fmaxf(gacc_l[bq * H_ + h], 1e-35f);
    ushort4 o;
    o.x = f2bf(v.x * inv); o.y = f2bf(v.y * inv);
    o.z = f2bf(v.z * inv); o.w = f2bf(v.w * inv);
    *reinterpret_cast<ushort4*>(abuf + idx4) = o;
}

extern "C" void kernel_launch(void* const* d_in, const int* in_sizes, int n_in,
                              void* d_out, int out_size, void* d_ws, size_t ws_size,
                              hipStream_t stream) {
    (void)in_sizes; (void)n_in; (void)out_size; (void)d_ws; (void)ws_size;
    const float* x    = (const float*)d_in[0];
    const float* c    = (const float*)d_in[1];
    const int*   mask = (const int*)d_in[2];
    const float* ln_w = (const float*)d_in[3];
    const float* ln_b = (const float*)d_in[4];
    const float* Wq   = (const float*)d_in[5];
    const float* Wo   = (const float*)d_in[6];
    float* out  = (float*)d_out;                    // o: 1,048,576 fp32 (4 MB)
    float* out2 = out + (size_t)B_ * NX_ * D_;      // kv0: 8,388,608 fp32 (32 MB)

    // scratch inside out2 (float-slot offsets); kv0 runs LAST and overwrites.
    float* base = out2;
    unsigned short* qbf      = (unsigned short*)(base);               // [0,       524288)
    unsigned*       maskbits = (unsigned*)(base + 524288);            // [524288,  655360)
    float*          gacc     = base + 655360;                         // [655360,  1703936)
    float*          gacc_l   = base + 1703936;                        // [1703936, 1720320)
    unsigned short* WqT      = (unsigned short*)(base + 1720320);     // [1720320, 2244608)
    unsigned short* WoT      = (unsigned short*)(base + 2244608);     // [2244608, 2768896)
    unsigned short* xnb      = (unsigned short*)(base + 2768896);     // [2768896, 3293184)
    unsigned short* abuf     = (unsigned short*)(base + 3293184);     // [3293184, 3817472)
    unsigned short* cbf      = (unsigned short*)(base + 3817472);     // [3817472, 8011776)

    const int M = B_ * NX_;   // 1024

    ln_kernel<<<M, 256, 0, stream>>>(x, ln_w, ln_b, xnb);
    tcast_kernel<<<dim3(16, 16), 256, 0, stream>>>(Wq, WqT);
    tcast_kernel<<<dim3(16, 16), 256, 0, stream>>>(Wo, WoT);
    pack_mask_kernel<<<(B_ * NX_ * NC_ / 32) / 256, 256, 0, stream>>>(mask, maskbits);
    cast_kernel<<<(B_ * NC_ * D_ / 4) / 256, 256, 0, stream>>>(c, cbf);
    hipMemsetAsync(gacc, 0, (size_t)(1048576 + 16384) * sizeof(float), stream);
    gemm_bt_kernel<<<dim3(16, 16), 256, 0, stream>>>(xnb, WqT, nullptr, qbf);
    attn_kernel<<<NSPLIT * 256, 256, 0, stream>>>(qbf, cbf, maskbits, gacc, gacc_l);
    combine_kernel<<<(B_ * NX_ * D_ / 4) / 256, 256, 0, stream>>>(gacc, gacc_l, abuf);
    gemm_bt_kernel<<<dim3(16, 16), 256, 0, stream>>>(abuf, WoT, out, nullptr);
    kv0_kernel<<<(B_ * H_ * NC_ * HD_ / 4) / 256, 256, 0, stream>>>(c, out2);
}

// Round 8
// 222.990 us; speedup vs baseline: 1.0398x; 1.0398x over previous
//
#include <hip/hip_runtime.h>

#define B_  2
#define NX_ 512
#define NC_ 4096
#define D_  1024
#define H_  16
#define HD_ 64
#define NT_ (NX_ + NC_)   // 4608
#define NSPLIT 4
#define KBS (NT_ / 64 / NSPLIT)   // 18 key-blocks per split

typedef float  floatx4  __attribute__((ext_vector_type(4)));
typedef __bf16 bf16x8   __attribute__((ext_vector_type(8)));
typedef unsigned short ushort8v __attribute__((ext_vector_type(8)));

__device__ __forceinline__ bf16x8 as_bf16x8(ushort8v u) {
    union { ushort8v u; bf16x8 b; } c; c.u = u; return c.b;
}
// fp32 -> bf16 round-to-nearest-even
__device__ __forceinline__ unsigned short f2bf(float f) {
    unsigned u = __float_as_uint(f);
    u += 0x7FFF + ((u >> 16) & 1);
    return (unsigned short)(u >> 16);
}

// ================ prep: LN + tcast(Wq) + tcast(Wo) + pack_mask + cast(c) + zero(gacc) ================
// One launch, region-dispatched by blockIdx (block-uniform branches).
// regions: [0,1024) ln | [1024,1280) tcast Wq | [1280,1536) tcast Wo |
//          [1536,2048) pack_mask | [2048,10240) cast c | [10240,11280) zero gacc
__global__ __launch_bounds__(256)
void prep_kernel(const float* __restrict__ x, const float* __restrict__ lw,
                 const float* __restrict__ lb, const float* __restrict__ Wq,
                 const float* __restrict__ Wo, const int* __restrict__ mask,
                 const float* __restrict__ c,
                 unsigned short* __restrict__ xnb, unsigned short* __restrict__ WqT,
                 unsigned short* __restrict__ WoT, unsigned* __restrict__ bits,
                 unsigned short* __restrict__ cbf, float* __restrict__ gz) {
    int blk = blockIdx.x;
    int tid = threadIdx.x;
    if (blk < 1024) {
        // ---- LayerNorm row ----
        int row = blk;
        float4 v = reinterpret_cast<const float4*>(x)[(size_t)row * (D_ / 4) + tid];
        float s  = v.x + v.y + v.z + v.w;
        float s2 = v.x * v.x + v.y * v.y + v.z * v.z + v.w * v.w;
        #pragma unroll
        for (int off = 32; off > 0; off >>= 1) {
            s  += __shfl_down(s, off);
            s2 += __shfl_down(s2, off);
        }
        __shared__ float sm[4], sm2[4], stat[2];
        int wv = tid >> 6;
        if ((tid & 63) == 0) { sm[wv] = s; sm2[wv] = s2; }
        __syncthreads();
        if (tid == 0) {
            float S  = sm[0] + sm[1] + sm[2] + sm[3];
            float S2 = sm2[0] + sm2[1] + sm2[2] + sm2[3];
            float mu  = S * (1.0f / D_);
            float var = fmaxf(S2 * (1.0f / D_) - mu * mu, 0.0f);
            stat[0] = mu;
            stat[1] = rsqrtf(var + 1e-5f);
        }
        __syncthreads();
        float mu = stat[0], rs = stat[1];
        float4 w4 = reinterpret_cast<const float4*>(lw)[tid];
        float4 b4 = reinterpret_cast<const float4*>(lb)[tid];
        ushort4 o;
        o.x = f2bf((v.x - mu) * rs * w4.x + b4.x);
        o.y = f2bf((v.y - mu) * rs * w4.y + b4.y);
        o.z = f2bf((v.z - mu) * rs * w4.z + b4.z);
        o.w = f2bf((v.w - mu) * rs * w4.w + b4.w);
        reinterpret_cast<ushort4*>(xnb)[(size_t)row * (D_ / 4) + tid] = o;
    } else if (blk < 1536) {
        // ---- transpose+cast W -> WT (64x64 tile) ----
        int which = (blk - 1024) >> 8;
        int t = (blk - 1024) & 255;
        const float* W = which ? Wo : Wq;
        unsigned short* WT = which ? WoT : WqT;
        __shared__ unsigned short T[64][72];
        int row0 = (t >> 4) * 64, col0 = (t & 15) * 64;
        int r = tid >> 2, ch = (tid & 3) * 16;
        const float* src = W + (size_t)(row0 + r) * D_ + col0 + ch;
        unsigned short vals[16];
        #pragma unroll
        for (int k = 0; k < 4; ++k) {
            float4 v = reinterpret_cast<const float4*>(src)[k];
            vals[k*4+0] = f2bf(v.x); vals[k*4+1] = f2bf(v.y);
            vals[k*4+2] = f2bf(v.z); vals[k*4+3] = f2bf(v.w);
        }
        #pragma unroll
        for (int i = 0; i < 16; ++i) T[ch + i][r] = vals[i];
        __syncthreads();
        unsigned short* dst = WT + (size_t)(col0 + r) * D_ + row0 + ch;
        uint4 o0 = *reinterpret_cast<uint4*>(&T[r][ch]);
        uint4 o1 = *reinterpret_cast<uint4*>(&T[r][ch + 8]);
        *reinterpret_cast<uint4*>(dst)     = o0;
        *reinterpret_cast<uint4*>(dst + 8) = o1;
    } else if (blk < 2048) {
        // ---- pack mask to bits ----
        size_t w = (size_t)(blk - 1536) * 256 + tid;
        const int* src = mask + w * 32;
        unsigned b = 0;
        #pragma unroll
        for (int k = 0; k < 8; ++k) {
            int4 v = reinterpret_cast<const int4*>(src)[k];
            b |= (v.x != 0 ? 1u : 0u) << (k * 4 + 0);
            b |= (v.y != 0 ? 1u : 0u) << (k * 4 + 1);
            b |= (v.z != 0 ? 1u : 0u) << (k * 4 + 2);
            b |= (v.w != 0 ? 1u : 0u) << (k * 4 + 3);
        }
        bits[w] = b;
    } else if (blk < 10240) {
        // ---- cast c fp32 -> bf16 ----
        size_t i = ((size_t)(blk - 2048) * 256 + tid) * 4;
        float4 v = *reinterpret_cast<const float4*>(c + i);
        ushort4 o;
        o.x = f2bf(v.x); o.y = f2bf(v.y); o.z = f2bf(v.z); o.w = f2bf(v.w);
        *reinterpret_cast<ushort4*>(cbf + i) = o;
    } else {
        // ---- zero gacc + gacc_l (contiguous 1,064,960 floats) ----
        size_t i = ((size_t)(blk - 10240) * 256 + tid) * 4;
        float4 z = {0.f, 0.f, 0.f, 0.f};
        *reinterpret_cast<float4*>(gz + i) = z;
    }
}

// ---------------- kv0: out2[b,h,n,d] = c[b,n,h*64+d] (fp32) — runs LAST ----------------
__global__ __launch_bounds__(256)
void kv0_kernel(const float* __restrict__ c, float* __restrict__ out2) {
    size_t i = (size_t)blockIdx.x * 256 + threadIdx.x;
    int d4 = (int)(i & 15);
    size_t r = i >> 4;
    int n = (int)(r % NC_);
    size_t r2 = r / NC_;
    int h = (int)(r2 & (H_ - 1));
    int b = (int)(r2 >> 4);
    float4 v = *reinterpret_cast<const float4*>(c + ((size_t)(b * NC_ + n)) * D_ + h * HD_ + d4 * 4);
    reinterpret_cast<float4*>(out2)[i] = v;
}

// ---------------- MFMA GEMM (q-proj): qbf = xnb @ Wq, B given as WqT; out bf16 ----------------
__global__ __launch_bounds__(256)
void gemm_bt_kernel(const unsigned short* __restrict__ A, const unsigned short* __restrict__ BT,
                    unsigned short* __restrict__ Cb) {
    __shared__ unsigned short As[64][72];
    __shared__ unsigned short Bs[64][72];
    int tid = threadIdx.x;
    int lane = tid & 63, wave = tid >> 6;
    int m16 = lane & 15, g = lane >> 4, g8 = g * 8;
    int row0 = blockIdx.y * 64, col0 = blockIdx.x * 64;
    int r = tid >> 2, ch = (tid & 3) * 16;

    floatx4 acc[4];
    #pragma unroll
    for (int t = 0; t < 4; ++t) acc[t] = (floatx4){0.f, 0.f, 0.f, 0.f};

    for (int kc = 0; kc < 16; ++kc) {
        int k0 = kc * 64;
        const unsigned short* asrc = A  + (size_t)(row0 + r) * D_ + k0 + ch;
        const unsigned short* bsrc = BT + (size_t)(col0 + r) * D_ + k0 + ch;
        uint4 a0 = *reinterpret_cast<const uint4*>(asrc);
        uint4 a1 = *reinterpret_cast<const uint4*>(asrc + 8);
        uint4 b0 = *reinterpret_cast<const uint4*>(bsrc);
        uint4 b1 = *reinterpret_cast<const uint4*>(bsrc + 8);
        *reinterpret_cast<uint4*>(&As[r][ch])     = a0;
        *reinterpret_cast<uint4*>(&As[r][ch + 8]) = a1;
        *reinterpret_cast<uint4*>(&Bs[r][ch])     = b0;
        *reinterpret_cast<uint4*>(&Bs[r][ch + 8]) = b1;
        __syncthreads();
        bf16x8 fa0 = as_bf16x8(*reinterpret_cast<ushort8v*>(&As[16 * wave + m16][g8]));
        bf16x8 fa1 = as_bf16x8(*reinterpret_cast<ushort8v*>(&As[16 * wave + m16][32 + g8]));
        #pragma unroll
        for (int t = 0; t < 4; ++t) {
            bf16x8 fb0 = as_bf16x8(*reinterpret_cast<ushort8v*>(&Bs[16 * t + m16][g8]));
            bf16x8 fb1 = as_bf16x8(*reinterpret_cast<ushort8v*>(&Bs[16 * t + m16][32 + g8]));
            acc[t] = __builtin_amdgcn_mfma_f32_16x16x32_bf16(fa0, fb0, acc[t], 0, 0, 0);
            acc[t] = __builtin_amdgcn_mfma_f32_16x16x32_bf16(fa1, fb1, acc[t], 0, 0, 0);
        }
        __syncthreads();
    }
    #pragma unroll
    for (int t = 0; t < 4; ++t)
        #pragma unroll
        for (int reg = 0; reg < 4; ++reg)
            Cb[(size_t)(row0 + 16 * wave + g * 4 + reg) * D_ + col0 + 16 * t + m16] = f2bf(acc[t][reg]);
}

// ---------------- MFMA GEMM (o-proj, fused combine): out = (gacc/l) @ Wo ----------------
// A is staged from fp32 gacc, normalized by 1/gacc_l[row, h=kc] during staging (h == k-chunk).
__global__ __launch_bounds__(256)
void gemm_attn_kernel(const float* __restrict__ gacc, const float* __restrict__ gacc_l,
                      const unsigned short* __restrict__ BT, float* __restrict__ out) {
    __shared__ unsigned short As[64][72];
    __shared__ unsigned short Bs[64][72];
    int tid = threadIdx.x;
    int lane = tid & 63, wave = tid >> 6;
    int m16 = lane & 15, g = lane >> 4, g8 = g * 8;
    int row0 = blockIdx.y * 64, col0 = blockIdx.x * 64;
    int r = tid >> 2, ch = (tid & 3) * 16;

    floatx4 acc[4];
    #pragma unroll
    for (int t = 0; t < 4; ++t) acc[t] = (floatx4){0.f, 0.f, 0.f, 0.f};

    for (int kc = 0; kc < 16; ++kc) {
        int k0 = kc * 64;
        int row = row0 + r;
        float inv = 1.0f / fmaxf(gacc_l[(size_t)row * H_ + kc], 1e-35f);
        const float* asrc = gacc + (size_t)row * D_ + k0 + ch;
        const unsigned short* bsrc = BT + (size_t)(col0 + r) * D_ + k0 + ch;
        unsigned short av[16];
        #pragma unroll
        for (int t = 0; t < 4; ++t) {
            float4 v = reinterpret_cast<const float4*>(asrc)[t];
            av[t*4+0] = f2bf(v.x * inv); av[t*4+1] = f2bf(v.y * inv);
            av[t*4+2] = f2bf(v.z * inv); av[t*4+3] = f2bf(v.w * inv);
        }
        uint4 b0 = *reinterpret_cast<const uint4*>(bsrc);
        uint4 b1 = *reinterpret_cast<const uint4*>(bsrc + 8);
        *reinterpret_cast<uint4*>(&As[r][ch])     = *reinterpret_cast<uint4*>(&av[0]);
        *reinterpret_cast<uint4*>(&As[r][ch + 8]) = *reinterpret_cast<uint4*>(&av[8]);
        *reinterpret_cast<uint4*>(&Bs[r][ch])     = b0;
        *reinterpret_cast<uint4*>(&Bs[r][ch + 8]) = b1;
        __syncthreads();
        bf16x8 fa0 = as_bf16x8(*reinterpret_cast<ushort8v*>(&As[16 * wave + m16][g8]));
        bf16x8 fa1 = as_bf16x8(*reinterpret_cast<ushort8v*>(&As[16 * wave + m16][32 + g8]));
        #pragma unroll
        for (int t = 0; t < 4; ++t) {
            bf16x8 fb0 = as_bf16x8(*reinterpret_cast<ushort8v*>(&Bs[16 * t + m16][g8]));
            bf16x8 fb1 = as_bf16x8(*reinterpret_cast<ushort8v*>(&Bs[16 * t + m16][32 + g8]));
            acc[t] = __builtin_amdgcn_mfma_f32_16x16x32_bf16(fa0, fb0, acc[t], 0, 0, 0);
            acc[t] = __builtin_amdgcn_mfma_f32_16x16x32_bf16(fa1, fb1, acc[t], 0, 0, 0);
        }
        __syncthreads();
    }
    #pragma unroll
    for (int t = 0; t < 4; ++t)
        #pragma unroll
        for (int reg = 0; reg < 4; ++reg)
            out[(size_t)(row0 + 16 * wave + g * 4 + reg) * D_ + col0 + 16 * t + m16] = acc[t][reg];
}

// ---------------- MFMA flash attention, split-K x4, atomic accumulation ----------------
// grid 1024, XCD-swizzled: blk = [bhhi:2][inner:5][xcd:3]; all 32 blocks of one (b,h)
// land on one XCD -> its 590KB K-slab stays in that XCD's L2 across the 32-fold re-read.
// Linear fixed-ref softmax p=exp(s/8-64): split partials atomically add into gacc.
// Kts: [64][72] + chunk rotation (R7). Ps: [64][64] pad-free + chunk rotation
// pc=(col>>3 + 2*((row>>2)&3))&7 -> writes 32 banks x 2-way (free), reads b128 aligned.
__global__ __launch_bounds__(256, 4)
void attn_kernel(const unsigned short* __restrict__ qbf,
                 const unsigned short* __restrict__ cbf,
                 const unsigned* __restrict__ maskbits,
                 float* __restrict__ gacc, float* __restrict__ gacc_l) {
    int blk   = blockIdx.x;
    int bh    = ((blk >> 8) << 3) | (blk & 7);   // 0..31
    int inner = (blk >> 3) & 31;
    int qt    = inner & 7;
    int split = inner >> 3;
    int h  = bh & 15;
    int b  = bh >> 4;
    int tid  = threadIdx.x;
    int lane = tid & 63;
    int wave = tid >> 6;
    int m16  = lane & 15;
    int g    = lane >> 4;
    int g8   = g * 8;

    __shared__ unsigned short Ks [64][72];
    __shared__ unsigned short Kts[64][72];
    __shared__ unsigned short Ps [64][64];

    // Q A-frags direct from global (once)
    const unsigned short* qrow = qbf + ((size_t)(b * NX_ + qt * 64 + 16 * wave + m16)) * D_ + h * HD_;
    bf16x8 qa0 = as_bf16x8(*reinterpret_cast<const ushort8v*>(qrow + g8));
    bf16x8 qa1 = as_bf16x8(*reinterpret_cast<const ushort8v*>(qrow + 32 + g8));

    floatx4 acc_o[4];
    #pragma unroll
    for (int td = 0; td < 4; ++td) acc_o[td] = (floatx4){0.f, 0.f, 0.f, 0.f};
    float l_acc[4] = {0.f, 0.f, 0.f, 0.f};

    int keyl = tid >> 2, dch = (tid & 3) * 16;
    int prsw = 2 * ((m16 >> 2) & 3);   // Ps read-side rotation for row 16w+m16

    for (int i = 0; i < KBS; ++i) {
        int kb = split * KBS + i;
        __syncthreads();                       // prior PV done with Ks/Kts
        // ---- stage K tile (bf16): Ks rows + rotated Kts ----
        const unsigned short* src = (kb < 8)
            ? qbf + ((size_t)(b * NX_ + kb * 64 + keyl)) * D_ + h * HD_ + dch
            : cbf + ((size_t)(b * NC_ + kb * 64 - NX_ + keyl)) * D_ + h * HD_ + dch;
        union { uint4 v[2]; unsigned short s[16]; } u;
        u.v[0] = *reinterpret_cast<const uint4*>(src);
        u.v[1] = *reinterpret_cast<const uint4*>(src + 8);
        *reinterpret_cast<uint4*>(&Ks[keyl][dch])     = u.v[0];
        *reinterpret_cast<uint4*>(&Ks[keyl][dch + 8]) = u.v[1];
        #pragma unroll
        for (int k = 0; k < 16; ++k) {
            int d = dch + k;
            int pc = ((keyl >> 3) + (d >> 3)) & 7;
            Kts[d][pc * 8 + (keyl & 7)] = u.s[k];
        }
        __syncthreads();

        // ---- S = Q @ K^T ----
        floatx4 accs[4];
        #pragma unroll
        for (int t = 0; t < 4; ++t) {
            bf16x8 b0 = as_bf16x8(*reinterpret_cast<ushort8v*>(&Ks[16 * t + m16][g8]));
            bf16x8 b1 = as_bf16x8(*reinterpret_cast<ushort8v*>(&Ks[16 * t + m16][32 + g8]));
            floatx4 d = (floatx4){0.f, 0.f, 0.f, 0.f};
            d = __builtin_amdgcn_mfma_f32_16x16x32_bf16(qa0, b0, d, 0, 0, 0);
            d = __builtin_amdgcn_mfma_f32_16x16x32_bf16(qa1, b1, d, 0, 0, 0);
            accs[t] = d;
        }

        unsigned mw0[4], mw1[4];
        if (kb >= 8) {
            #pragma unroll
            for (int r = 0; r < 4; ++r) {
                size_t mi = ((size_t)(b * NX_ + qt * 64 + 16 * wave + g * 4 + r)) * (NC_ / 32)
                          + (size_t)(kb - 8) * 2;
                uint2 w = *reinterpret_cast<const uint2*>(&maskbits[mi]);
                mw0[r] = w.x; mw1[r] = w.y;
            }
        }

        // ---- p = exp(s/8 - 64), masked -> 0; rotated P store; row partial sums ----
        float psum[4] = {0.f, 0.f, 0.f, 0.f};
        #pragma unroll
        for (int t = 0; t < 4; ++t) {
            int cc = 2 * t + (m16 >> 3);
            #pragma unroll
            for (int r = 0; r < 4; ++r) {
                float s = accs[t][r] * 0.125f;
                float p = __expf(fminf(s, 64.0f) - 64.0f);
                if (kb >= 8) {
                    unsigned w = (t < 2) ? mw0[r] : mw1[r];
                    unsigned bit = (w >> ((16 * t + m16) & 31)) & 1u;
                    p = bit ? p : 0.0f;
                }
                psum[r] += p;
                int prow = 16 * wave + g * 4 + r;
                int pc = (cc + 2 * g) & 7;            // (prow>>2)&3 == g
                Ps[prow][pc * 8 + (m16 & 7)] = f2bf(p);
            }
        }
        #pragma unroll
        for (int r = 0; r < 4; ++r) {
            float v = psum[r];
            v += __shfl_xor(v, 1, 16);
            v += __shfl_xor(v, 2, 16);
            v += __shfl_xor(v, 4, 16);
            v += __shfl_xor(v, 8, 16);
            l_acc[r] += v;
        }
        asm volatile("s_waitcnt lgkmcnt(0)" ::: "memory");   // own-strip Ps round-trip

        // ---- O += P @ V (P frags from rotated Ps, V rows from rotated Kts) ----
        bf16x8 p0 = as_bf16x8(*reinterpret_cast<ushort8v*>(&Ps[16 * wave + m16][((g + prsw) & 7) * 8]));
        bf16x8 p1 = as_bf16x8(*reinterpret_cast<ushort8v*>(&Ps[16 * wave + m16][((4 + g + prsw) & 7) * 8]));
        #pragma unroll
        for (int td = 0; td < 4; ++td) {
            int row = 16 * td + m16;
            int rh = row >> 3;
            bf16x8 v0 = as_bf16x8(*reinterpret_cast<ushort8v*>(&Kts[row][((g + rh) & 7) * 8]));
            bf16x8 v1 = as_bf16x8(*reinterpret_cast<ushort8v*>(&Kts[row][((4 + g + rh) & 7) * 8]));
            acc_o[td] = __builtin_amdgcn_mfma_f32_16x16x32_bf16(p0, v0, acc_o[td], 0, 0, 0);
            acc_o[td] = __builtin_amdgcn_mfma_f32_16x16x32_bf16(p1, v1, acc_o[td], 0, 0, 0);
        }
    }

    // ---- epilogue: atomically accumulate partial O and l ----
    #pragma unroll
    for (int r = 0; r < 4; ++r) {
        int qrow_ = qt * 64 + 16 * wave + g * 4 + r;
        float* dst = gacc + ((size_t)(b * NX_ + qrow_)) * D_ + h * HD_;
        #pragma unroll
        for (int td = 0; td < 4; ++td)
            unsafeAtomicAdd(&dst[16 * td + m16], acc_o[td][r]);
        if (m16 == 0)
            unsafeAtomicAdd(&gacc_l[(size_t)(b * NX_ + qrow_) * H_ + h], l_acc[r]);
    }
}

extern "C" void kernel_launch(void* const* d_in, const int* in_sizes, int n_in,
                              void* d_out, int out_size, void* d_ws, size_t ws_size,
                              hipStream_t stream) {
    (void)in_sizes; (void)n_in; (void)out_size; (void)d_ws; (void)ws_size;
    const float* x    = (const float*)d_in[0];
    const float* c    = (const float*)d_in[1];
    const int*   mask = (const int*)d_in[2];
    const float* ln_w = (const float*)d_in[3];
    const float* ln_b = (const float*)d_in[4];
    const float* Wq   = (const float*)d_in[5];
    const float* Wo   = (const float*)d_in[6];
    float* out  = (float*)d_out;                    // o: 1,048,576 fp32 (4 MB)
    float* out2 = out + (size_t)B_ * NX_ * D_;      // kv0: 8,388,608 fp32 (32 MB)

    // scratch inside out2 (float-slot offsets); kv0 runs LAST and overwrites.
    float* base = out2;
    unsigned short* qbf      = (unsigned short*)(base);               // [0,       524288)
    unsigned*       maskbits = (unsigned*)(base + 524288);            // [524288,  655360)
    float*          gacc     = base + 655360;                         // [655360,  1703936)
    float*          gacc_l   = base + 1703936;                        // [1703936, 1720320)
    unsigned short* WqT      = (unsigned short*)(base + 1720320);     // [1720320, 2244608)
    unsigned short* WoT      = (unsigned short*)(base + 2244608);     // [2244608, 2768896)
    unsigned short* xnb      = (unsigned short*)(base + 2768896);     // [2768896, 3293184)
    unsigned short* cbf      = (unsigned short*)(base + 3817472);     // [3817472, 8011776)

    prep_kernel<<<11280, 256, 0, stream>>>(x, ln_w, ln_b, Wq, Wo, mask, c,
                                           xnb, WqT, WoT, maskbits, cbf, gacc);
    gemm_bt_kernel<<<dim3(16, 16), 256, 0, stream>>>(xnb, WqT, qbf);
    attn_kernel<<<NSPLIT * 256, 256, 0, stream>>>(qbf, cbf, maskbits, gacc, gacc_l);
    gemm_attn_kernel<<<dim3(16, 16), 256, 0, stream>>>(gacc, gacc_l, WoT, out);
    kv0_kernel<<<(B_ * H_ * NC_ * HD_ / 4) / 256, 256, 0, stream>>>(c, out2);
}

// Round 9
// 205.555 us; speedup vs baseline: 1.1280x; 1.0848x over previous
//
#include <hip/hip_runtime.h>

#define B_  2
#define NX_ 512
#define NC_ 4096
#define D_  1024
#define H_  16
#define HD_ 64
#define NT_ (NX_ + NC_)   // 4608
#define NSPLIT 4
#define KBS (NT_ / 64 / NSPLIT)   // 18 key-blocks per split

typedef float  floatx4  __attribute__((ext_vector_type(4)));
typedef __bf16 bf16x8   __attribute__((ext_vector_type(8)));
typedef unsigned short ushort8v __attribute__((ext_vector_type(8)));

__device__ __forceinline__ bf16x8 as_bf16x8(ushort8v u) {
    union { ushort8v u; bf16x8 b; } c; c.u = u; return c.b;
}
// fp32 -> bf16 round-to-nearest-even
__device__ __forceinline__ unsigned short f2bf(float f) {
    unsigned u = __float_as_uint(f);
    u += 0x7FFF + ((u >> 16) & 1);
    return (unsigned short)(u >> 16);
}

// ================ prep: LN + tcast(Wq) + tcast(Wo) + pack_mask + cast(c) + zero(gacc) ================
__global__ __launch_bounds__(256)
void prep_kernel(const float* __restrict__ x, const float* __restrict__ lw,
                 const float* __restrict__ lb, const float* __restrict__ Wq,
                 const float* __restrict__ Wo, const int* __restrict__ mask,
                 const float* __restrict__ c,
                 unsigned short* __restrict__ xnb, unsigned short* __restrict__ WqT,
                 unsigned short* __restrict__ WoT, unsigned* __restrict__ bits,
                 unsigned short* __restrict__ cbf, float* __restrict__ gz) {
    int blk = blockIdx.x;
    int tid = threadIdx.x;
    if (blk < 1024) {
        int row = blk;
        float4 v = reinterpret_cast<const float4*>(x)[(size_t)row * (D_ / 4) + tid];
        float s  = v.x + v.y + v.z + v.w;
        float s2 = v.x * v.x + v.y * v.y + v.z * v.z + v.w * v.w;
        #pragma unroll
        for (int off = 32; off > 0; off >>= 1) {
            s  += __shfl_down(s, off);
            s2 += __shfl_down(s2, off);
        }
        __shared__ float sm[4], sm2[4], stat[2];
        int wv = tid >> 6;
        if ((tid & 63) == 0) { sm[wv] = s; sm2[wv] = s2; }
        __syncthreads();
        if (tid == 0) {
            float S  = sm[0] + sm[1] + sm[2] + sm[3];
            float S2 = sm2[0] + sm2[1] + sm2[2] + sm2[3];
            float mu  = S * (1.0f / D_);
            float var = fmaxf(S2 * (1.0f / D_) - mu * mu, 0.0f);
            stat[0] = mu;
            stat[1] = rsqrtf(var + 1e-5f);
        }
        __syncthreads();
        float mu = stat[0], rs = stat[1];
        float4 w4 = reinterpret_cast<const float4*>(lw)[tid];
        float4 b4 = reinterpret_cast<const float4*>(lb)[tid];
        ushort4 o;
        o.x = f2bf((v.x - mu) * rs * w4.x + b4.x);
        o.y = f2bf((v.y - mu) * rs * w4.y + b4.y);
        o.z = f2bf((v.z - mu) * rs * w4.z + b4.z);
        o.w = f2bf((v.w - mu) * rs * w4.w + b4.w);
        reinterpret_cast<ushort4*>(xnb)[(size_t)row * (D_ / 4) + tid] = o;
    } else if (blk < 1536) {
        int which = (blk - 1024) >> 8;
        int t = (blk - 1024) & 255;
        const float* W = which ? Wo : Wq;
        unsigned short* WT = which ? WoT : WqT;
        __shared__ unsigned short T[64][72];
        int row0 = (t >> 4) * 64, col0 = (t & 15) * 64;
        int r = tid >> 2, ch = (tid & 3) * 16;
        const float* src = W + (size_t)(row0 + r) * D_ + col0 + ch;
        unsigned short vals[16];
        #pragma unroll
        for (int k = 0; k < 4; ++k) {
            float4 v = reinterpret_cast<const float4*>(src)[k];
            vals[k*4+0] = f2bf(v.x); vals[k*4+1] = f2bf(v.y);
            vals[k*4+2] = f2bf(v.z); vals[k*4+3] = f2bf(v.w);
        }
        #pragma unroll
        for (int i = 0; i < 16; ++i) T[ch + i][r] = vals[i];
        __syncthreads();
        unsigned short* dst = WT + (size_t)(col0 + r) * D_ + row0 + ch;
        uint4 o0 = *reinterpret_cast<uint4*>(&T[r][ch]);
        uint4 o1 = *reinterpret_cast<uint4*>(&T[r][ch + 8]);
        *reinterpret_cast<uint4*>(dst)     = o0;
        *reinterpret_cast<uint4*>(dst + 8) = o1;
    } else if (blk < 2048) {
        size_t w = (size_t)(blk - 1536) * 256 + tid;
        const int* src = mask + w * 32;
        unsigned b = 0;
        #pragma unroll
        for (int k = 0; k < 8; ++k) {
            int4 v = reinterpret_cast<const int4*>(src)[k];
            b |= (v.x != 0 ? 1u : 0u) << (k * 4 + 0);
            b |= (v.y != 0 ? 1u : 0u) << (k * 4 + 1);
            b |= (v.z != 0 ? 1u : 0u) << (k * 4 + 2);
            b |= (v.w != 0 ? 1u : 0u) << (k * 4 + 3);
        }
        bits[w] = b;
    } else if (blk < 10240) {
        size_t i = ((size_t)(blk - 2048) * 256 + tid) * 4;
        float4 v = *reinterpret_cast<const float4*>(c + i);
        ushort4 o;
        o.x = f2bf(v.x); o.y = f2bf(v.y); o.z = f2bf(v.z); o.w = f2bf(v.w);
        *reinterpret_cast<ushort4*>(cbf + i) = o;
    } else {
        size_t i = ((size_t)(blk - 10240) * 256 + tid) * 4;
        float4 z = {0.f, 0.f, 0.f, 0.f};
        *reinterpret_cast<float4*>(gz + i) = z;
    }
}

// ---------------- kv0: out2[b,h,n,d] = c[b,n,h*64+d] (fp32) — runs LAST ----------------
__global__ __launch_bounds__(256)
void kv0_kernel(const float* __restrict__ c, float* __restrict__ out2) {
    size_t i = (size_t)blockIdx.x * 256 + threadIdx.x;
    int d4 = (int)(i & 15);
    size_t r = i >> 4;
    int n = (int)(r % NC_);
    size_t r2 = r / NC_;
    int h = (int)(r2 & (H_ - 1));
    int b = (int)(r2 >> 4);
    float4 v = *reinterpret_cast<const float4*>(c + ((size_t)(b * NC_ + n)) * D_ + h * HD_ + d4 * 4);
    reinterpret_cast<float4*>(out2)[i] = v;
}

// ---------------- MFMA GEMM (q-proj): qbf = xnb @ Wq (B given as WqT); out bf16 ----------------
__global__ __launch_bounds__(256)
void gemm_bt_kernel(const unsigned short* __restrict__ A, const unsigned short* __restrict__ BT,
                    unsigned short* __restrict__ Cb) {
    __shared__ unsigned short As[64][72];
    __shared__ unsigned short Bs[64][72];
    int tid = threadIdx.x;
    int lane = tid & 63, wave = tid >> 6;
    int m16 = lane & 15, g = lane >> 4, g8 = g * 8;
    int row0 = blockIdx.y * 64, col0 = blockIdx.x * 64;
    int r = tid >> 2, ch = (tid & 3) * 16;

    floatx4 acc[4];
    #pragma unroll
    for (int t = 0; t < 4; ++t) acc[t] = (floatx4){0.f, 0.f, 0.f, 0.f};

    for (int kc = 0; kc < 16; ++kc) {
        int k0 = kc * 64;
        const unsigned short* asrc = A  + (size_t)(row0 + r) * D_ + k0 + ch;
        const unsigned short* bsrc = BT + (size_t)(col0 + r) * D_ + k0 + ch;
        uint4 a0 = *reinterpret_cast<const uint4*>(asrc);
        uint4 a1 = *reinterpret_cast<const uint4*>(asrc + 8);
        uint4 b0 = *reinterpret_cast<const uint4*>(bsrc);
        uint4 b1 = *reinterpret_cast<const uint4*>(bsrc + 8);
        *reinterpret_cast<uint4*>(&As[r][ch])     = a0;
        *reinterpret_cast<uint4*>(&As[r][ch + 8]) = a1;
        *reinterpret_cast<uint4*>(&Bs[r][ch])     = b0;
        *reinterpret_cast<uint4*>(&Bs[r][ch + 8]) = b1;
        __syncthreads();
        bf16x8 fa0 = as_bf16x8(*reinterpret_cast<ushort8v*>(&As[16 * wave + m16][g8]));
        bf16x8 fa1 = as_bf16x8(*reinterpret_cast<ushort8v*>(&As[16 * wave + m16][32 + g8]));
        #pragma unroll
        for (int t = 0; t < 4; ++t) {
            bf16x8 fb0 = as_bf16x8(*reinterpret_cast<ushort8v*>(&Bs[16 * t + m16][g8]));
            bf16x8 fb1 = as_bf16x8(*reinterpret_cast<ushort8v*>(&Bs[16 * t + m16][32 + g8]));
            acc[t] = __builtin_amdgcn_mfma_f32_16x16x32_bf16(fa0, fb0, acc[t], 0, 0, 0);
            acc[t] = __builtin_amdgcn_mfma_f32_16x16x32_bf16(fa1, fb1, acc[t], 0, 0, 0);
        }
        __syncthreads();
    }
    #pragma unroll
    for (int t = 0; t < 4; ++t)
        #pragma unroll
        for (int reg = 0; reg < 4; ++reg)
            Cb[(size_t)(row0 + 16 * wave + g * 4 + reg) * D_ + col0 + 16 * t + m16] = f2bf(acc[t][reg]);
}

// ---------------- MFMA GEMM (o-proj, fused combine): out = (gacc/l) @ Wo ----------------
__global__ __launch_bounds__(256)
void gemm_attn_kernel(const float* __restrict__ gacc, const float* __restrict__ gacc_l,
                      const unsigned short* __restrict__ BT, float* __restrict__ out) {
    __shared__ unsigned short As[64][72];
    __shared__ unsigned short Bs[64][72];
    int tid = threadIdx.x;
    int lane = tid & 63, wave = tid >> 6;
    int m16 = lane & 15, g = lane >> 4, g8 = g * 8;
    int row0 = blockIdx.y * 64, col0 = blockIdx.x * 64;
    int r = tid >> 2, ch = (tid & 3) * 16;

    floatx4 acc[4];
    #pragma unroll
    for (int t = 0; t < 4; ++t) acc[t] = (floatx4){0.f, 0.f, 0.f, 0.f};

    for (int kc = 0; kc < 16; ++kc) {
        int k0 = kc * 64;
        int row = row0 + r;
        float inv = 1.0f / fmaxf(gacc_l[(size_t)row * H_ + kc], 1e-35f);
        const float* asrc = gacc + (size_t)row * D_ + k0 + ch;
        const unsigned short* bsrc = BT + (size_t)(col0 + r) * D_ + k0 + ch;
        unsigned short av[16];
        #pragma unroll
        for (int t = 0; t < 4; ++t) {
            float4 v = reinterpret_cast<const float4*>(asrc)[t];
            av[t*4+0] = f2bf(v.x * inv); av[t*4+1] = f2bf(v.y * inv);
            av[t*4+2] = f2bf(v.z * inv); av[t*4+3] = f2bf(v.w * inv);
        }
        uint4 b0 = *reinterpret_cast<const uint4*>(bsrc);
        uint4 b1 = *reinterpret_cast<const uint4*>(bsrc + 8);
        *reinterpret_cast<uint4*>(&As[r][ch])     = *reinterpret_cast<uint4*>(&av[0]);
        *reinterpret_cast<uint4*>(&As[r][ch + 8]) = *reinterpret_cast<uint4*>(&av[8]);
        *reinterpret_cast<uint4*>(&Bs[r][ch])     = b0;
        *reinterpret_cast<uint4*>(&Bs[r][ch + 8]) = b1;
        __syncthreads();
        bf16x8 fa0 = as_bf16x8(*reinterpret_cast<ushort8v*>(&As[16 * wave + m16][g8]));
        bf16x8 fa1 = as_bf16x8(*reinterpret_cast<ushort8v*>(&As[16 * wave + m16][32 + g8]));
        #pragma unroll
        for (int t = 0; t < 4; ++t) {
            bf16x8 fb0 = as_bf16x8(*reinterpret_cast<ushort8v*>(&Bs[16 * t + m16][g8]));
            bf16x8 fb1 = as_bf16x8(*reinterpret_cast<ushort8v*>(&Bs[16 * t + m16][32 + g8]));
            acc[t] = __builtin_amdgcn_mfma_f32_16x16x32_bf16(fa0, fb0, acc[t], 0, 0, 0);
            acc[t] = __builtin_amdgcn_mfma_f32_16x16x32_bf16(fa1, fb1, acc[t], 0, 0, 0);
        }
        __syncthreads();
    }
    #pragma unroll
    for (int t = 0; t < 4; ++t)
        #pragma unroll
        for (int reg = 0; reg < 4; ++reg)
            out[(size_t)(row0 + 16 * wave + g * 4 + reg) * D_ + col0 + 16 * t + m16] = acc[t][reg];
}

// ---------------- MFMA flash attention, split-K x4, atomic accumulation ----------------
// R9: DS-pressure diet. Staging = 4keys x 4dims per thread: 4 b64 global loads,
// 4 b64 Ks writes, in-register 4x4 u16 transpose (8 v_perm) -> 4 b64 Kts writes
// (replaces 16 scalar b16). Row-sum l via MFMA with all-ones B operand
// (replaces 16 ds_swizzle shuffles). p = exp2(min(s*C1,C2)-C2), truncating bf16.
__global__ __launch_bounds__(256, 4)
void attn_kernel(const unsigned short* __restrict__ qbf,
                 const unsigned short* __restrict__ cbf,
                 const unsigned* __restrict__ maskbits,
                 float* __restrict__ gacc, float* __restrict__ gacc_l) {
    int blk   = blockIdx.x;
    int bh    = ((blk >> 8) << 3) | (blk & 7);   // XCD swizzle: one (b,h) per XCD group
    int inner = (blk >> 3) & 31;
    int qt    = inner & 7;
    int split = inner >> 3;
    int h  = bh & 15;
    int b  = bh >> 4;
    int tid  = threadIdx.x;
    int lane = tid & 63;
    int wave = tid >> 6;
    int m16  = lane & 15;
    int g    = lane >> 4;
    int g8   = g * 8;

    __shared__ unsigned short Ks [64][72];
    __shared__ unsigned short Kts[64][72];
    __shared__ unsigned short Ps [64][64];

    const unsigned short* qrow = qbf + ((size_t)(b * NX_ + qt * 64 + 16 * wave + m16)) * D_ + h * HD_;
    bf16x8 qa0 = as_bf16x8(*reinterpret_cast<const ushort8v*>(qrow + g8));
    bf16x8 qa1 = as_bf16x8(*reinterpret_cast<const ushort8v*>(qrow + 32 + g8));

    floatx4 acc_o[4];
    #pragma unroll
    for (int td = 0; td < 4; ++td) acc_o[td] = (floatx4){0.f, 0.f, 0.f, 0.f};
    floatx4 acc_l = (floatx4){0.f, 0.f, 0.f, 0.f};

    ushort8v ones_u;
    #pragma unroll
    for (int j = 0; j < 8; ++j) ones_u[j] = 0x3F80;   // bf16 1.0
    bf16x8 onesf = as_bf16x8(ones_u);

    // staging mapping: thread = (Kg, Dg): keys 4Kg..4Kg+3, dims 4Dg..4Dg+3
    int Kg = tid >> 4;          // 0..15
    int Dg = tid & 15;          // 0..15
    int pcst = ((Kg >> 1) + (Dg >> 1)) & 7;   // Kts chunk rotation (uniform per thread)
    int prsw = 2 * ((m16 >> 2) & 3);          // Ps read-side rotation

    for (int i = 0; i < KBS; ++i) {
        int kb = split * KBS + i;
        __syncthreads();
        // ---- stage K tile: 4 b64 loads, 4 b64 Ks writes, reg transpose, 4 b64 Kts writes ----
        const unsigned short* src = (kb < 8)
            ? qbf + ((size_t)(b * NX_ + kb * 64 + 4 * Kg)) * D_ + h * HD_ + 4 * Dg
            : cbf + ((size_t)(b * NC_ + kb * 64 - NX_ + 4 * Kg)) * D_ + h * HD_ + 4 * Dg;
        uint2 rows[4];
        #pragma unroll
        for (int kk = 0; kk < 4; ++kk)
            rows[kk] = *reinterpret_cast<const uint2*>(src + (size_t)kk * D_);
        #pragma unroll
        for (int kk = 0; kk < 4; ++kk)
            *reinterpret_cast<uint2*>(&Ks[4 * Kg + kk][4 * Dg]) = rows[kk];
        #pragma unroll
        for (int i2 = 0; i2 < 4; ++i2) {
            unsigned sel = (i2 & 1) ? 0x07060302u : 0x05040100u;
            unsigned r0 = (i2 >> 1) ? rows[0].y : rows[0].x;
            unsigned r1 = (i2 >> 1) ? rows[1].y : rows[1].x;
            unsigned r2 = (i2 >> 1) ? rows[2].y : rows[2].x;
            unsigned r3 = (i2 >> 1) ? rows[3].y : rows[3].x;
            uint2 cw;
            cw.x = __builtin_amdgcn_perm(r1, r0, sel);   // (k0.d, k1.d)
            cw.y = __builtin_amdgcn_perm(r3, r2, sel);   // (k2.d, k3.d)
            *reinterpret_cast<uint2*>(&Kts[4 * Dg + i2][pcst * 8 + 4 * (Kg & 1)]) = cw;
        }
        __syncthreads();

        // ---- S = Q @ K^T ----
        floatx4 accs[4];
        #pragma unroll
        for (int t = 0; t < 4; ++t) {
            bf16x8 b0 = as_bf16x8(*reinterpret_cast<ushort8v*>(&Ks[16 * t + m16][g8]));
            bf16x8 b1 = as_bf16x8(*reinterpret_cast<ushort8v*>(&Ks[16 * t + m16][32 + g8]));
            floatx4 d = (floatx4){0.f, 0.f, 0.f, 0.f};
            d = __builtin_amdgcn_mfma_f32_16x16x32_bf16(qa0, b0, d, 0, 0, 0);
            d = __builtin_amdgcn_mfma_f32_16x16x32_bf16(qa1, b1, d, 0, 0, 0);
            accs[t] = d;
        }

        unsigned mw0[4], mw1[4];
        if (kb >= 8) {
            #pragma unroll
            for (int r = 0; r < 4; ++r) {
                size_t mi = ((size_t)(b * NX_ + qt * 64 + 16 * wave + g * 4 + r)) * (NC_ / 32)
                          + (size_t)(kb - 8) * 2;
                uint2 w = *reinterpret_cast<const uint2*>(&maskbits[mi]);
                mw0[r] = w.x; mw1[r] = w.y;
            }
        }

        // ---- p = exp2(min(s*C1,C2)-C2), masked -> 0; rotated Ps store (trunc bf16) ----
        const float C1 = 0.18033688011112042f;   // 0.125 * log2(e)
        const float C2 = 92.33248261689366f;     // 64 * 0.125 * log2(e)... = 64*log2(e)*0.125? (64 cap post-scale)
        #pragma unroll
        for (int t = 0; t < 4; ++t) {
            int cc = 2 * t + (m16 >> 3);
            #pragma unroll
            for (int r = 0; r < 4; ++r) {
                float e = fminf(accs[t][r] * C1, C2) - C2;
                float p = __builtin_amdgcn_exp2f(e);
                if (kb >= 8) {
                    unsigned w = (t < 2) ? mw0[r] : mw1[r];
                    unsigned bit = (w >> ((16 * t + m16) & 31)) & 1u;
                    p = bit ? p : 0.0f;
                }
                int prow = 16 * wave + g * 4 + r;
                int pc = (cc + 2 * g) & 7;
                Ps[prow][pc * 8 + (m16 & 7)] = (unsigned short)(__float_as_uint(p) >> 16);
            }
        }
        asm volatile("s_waitcnt lgkmcnt(0)" ::: "memory");   // own-strip Ps round-trip

        // ---- O += P @ V ; l += P @ ones (MFMA row-sum) ----
        bf16x8 p0 = as_bf16x8(*reinterpret_cast<ushort8v*>(&Ps[16 * wave + m16][((g + prsw) & 7) * 8]));
        bf16x8 p1 = as_bf16x8(*reinterpret_cast<ushort8v*>(&Ps[16 * wave + m16][((4 + g + prsw) & 7) * 8]));
        acc_l = __builtin_amdgcn_mfma_f32_16x16x32_bf16(p0, onesf, acc_l, 0, 0, 0);
        acc_l = __builtin_amdgcn_mfma_f32_16x16x32_bf16(p1, onesf, acc_l, 0, 0, 0);
        #pragma unroll
        for (int td = 0; td < 4; ++td) {
            int row = 16 * td + m16;
            int rh = row >> 3;
            bf16x8 v0 = as_bf16x8(*reinterpret_cast<ushort8v*>(&Kts[row][((g + rh) & 7) * 8]));
            bf16x8 v1 = as_bf16x8(*reinterpret_cast<ushort8v*>(&Kts[row][((4 + g + rh) & 7) * 8]));
            acc_o[td] = __builtin_amdgcn_mfma_f32_16x16x32_bf16(p0, v0, acc_o[td], 0, 0, 0);
            acc_o[td] = __builtin_amdgcn_mfma_f32_16x16x32_bf16(p1, v1, acc_o[td], 0, 0, 0);
        }
    }

    // ---- epilogue: atomically accumulate partial O and l ----
    #pragma unroll
    for (int r = 0; r < 4; ++r) {
        int qrow_ = qt * 64 + 16 * wave + g * 4 + r;
        float* dst = gacc + ((size_t)(b * NX_ + qrow_)) * D_ + h * HD_;
        #pragma unroll
        for (int td = 0; td < 4; ++td)
            unsafeAtomicAdd(&dst[16 * td + m16], acc_o[td][r]);
        if (m16 == 0)
            unsafeAtomicAdd(&gacc_l[(size_t)(b * NX_ + qrow_) * H_ + h], acc_l[r]);
    }
}

extern "C" void kernel_launch(void* const* d_in, const int* in_sizes, int n_in,
                              void* d_out, int out_size, void* d_ws, size_t ws_size,
                              hipStream_t stream) {
    (void)in_sizes; (void)n_in; (void)out_size; (void)d_ws; (void)ws_size;
    const float* x    = (const float*)d_in[0];
    const float* c    = (const float*)d_in[1];
    const int*   mask = (const int*)d_in[2];
    const float* ln_w = (const float*)d_in[3];
    const float* ln_b = (const float*)d_in[4];
    const float* Wq   = (const float*)d_in[5];
    const float* Wo   = (const float*)d_in[6];
    float* out  = (float*)d_out;                    // o: 1,048,576 fp32 (4 MB)
    float* out2 = out + (size_t)B_ * NX_ * D_;      // kv0: 8,388,608 fp32 (32 MB)

    // scratch inside out2 (float-slot offsets); kv0 runs LAST and overwrites.
    float* base = out2;
    unsigned short* qbf      = (unsigned short*)(base);               // [0,       524288)
    unsigned*       maskbits = (unsigned*)(base + 524288);            // [524288,  655360)
    float*          gacc     = base + 655360;                         // [655360,  1703936)
    float*          gacc_l   = base + 1703936;                        // [1703936, 1720320)
    unsigned short* WqT      = (unsigned short*)(base + 1720320);     // [1720320, 2244608)
    unsigned short* WoT      = (unsigned short*)(base + 2244608);     // [2244608, 2768896)
    unsigned short* xnb      = (unsigned short*)(base + 2768896);     // [2768896, 3293184)
    unsigned short* cbf      = (unsigned short*)(base + 3817472);     // [3817472, 8011776)

    prep_kernel<<<11280, 256, 0, stream>>>(x, ln_w, ln_b, Wq, Wo, mask, c,
                                           xnb, WqT, WoT, maskbits, cbf, gacc);
    gemm_bt_kernel<<<dim3(16, 16), 256, 0, stream>>>(xnb, WqT, qbf);
    attn_kernel<<<NSPLIT * 256, 256, 0, stream>>>(qbf, cbf, maskbits, gacc, gacc_l);
    gemm_attn_kernel<<<dim3(16, 16), 256, 0, stream>>>(gacc, gacc_l, WoT, out);
    kv0_kernel<<<(B_ * H_ * NC_ * HD_ / 4) / 256, 256, 0, stream>>>(c, out2);
}